// Round 13
// baseline (458.327 us; speedup 1.0000x reference)
//
#include <hip/hip_runtime.h>

// B=1024 groups, T=256 steps, S=16 states, M=4 measurements
#define NT 256
#define NSTEP 255
// ws layout (floats):
//  [0 .. 6144)       8 doubling elements E^{2^d}, d=0..7, 768 floats each (A,C,J)
//  [6144 .. 17664)   E^{16k}, k=1..15, 768 floats each
//  [17664 .. 120064) 16 chunk operator packs, 6400 floats each:
//      +0    HG  [k][m][j]        16*4*16 = 1024
//      +1024 HW  [k][s][m][n]     16*16*16 = 4096  (zero for s>=k)
//      +5120 GL  [i][j]           256
//      +5376 WL  [s][i][n]        16*16*4 = 1024
#define CHEOFF 6144
#define OPOFF  17664
#define OPSZ   6400
#define HW_O   1024
#define GL_O   5120
#define WL_O   5376
#define NEED_WS_BYTES 500000UL

__device__ __forceinline__ float dot4(float4 a, float4 b) {
    return a.x*b.x + a.y*b.y + a.z*b.z + a.w*b.w;
}

// ---------------- 16x16 matmul helpers (lane (q,j) owns rows q+4r, col j) ----
__device__ __forceinline__ void mm_nn(const float* A, const float* B,
                                      const float* E, float* D, int q, int j) {
    float bc[16];
#pragma unroll
    for (int k = 0; k < 16; ++k) bc[k] = B[k*16 + j];
    float4 b0 = make_float4(bc[0],bc[1],bc[2],bc[3]);
    float4 b1 = make_float4(bc[4],bc[5],bc[6],bc[7]);
    float4 b2 = make_float4(bc[8],bc[9],bc[10],bc[11]);
    float4 b3 = make_float4(bc[12],bc[13],bc[14],bc[15]);
#pragma unroll
    for (int r = 0; r < 4; ++r) {
        int i = q + 4*r;
        const float4* Ar = (const float4*)(A + i*16);
        float acc = E ? E[i*16 + j] : 0.f;
        acc += dot4(Ar[0], b0) + dot4(Ar[1], b1) + dot4(Ar[2], b2) + dot4(Ar[3], b3);
        D[i*16 + j] = acc;
    }
}
__device__ __forceinline__ void mm_nt(const float* A, const float* B,
                                      const float* E, float* D, int q, int j) {
    const float4* Bj = (const float4*)(B + j*16);
    float4 c0 = Bj[0], c1 = Bj[1], c2 = Bj[2], c3 = Bj[3];
#pragma unroll
    for (int r = 0; r < 4; ++r) {
        int i = q + 4*r;
        const float4* Ar = (const float4*)(A + i*16);
        float acc = E ? E[i*16 + j] : 0.f;
        acc += dot4(Ar[0], c0) + dot4(Ar[1], c1) + dot4(Ar[2], c2) + dot4(Ar[3], c3);
        D[i*16 + j] = acc;
    }
}
__device__ __forceinline__ void mm_tn(const float* A, const float* B,
                                      const float* E, float* D, int q, int j) {
    float bc[16];
#pragma unroll
    for (int k = 0; k < 16; ++k) bc[k] = B[k*16 + j];
#pragma unroll
    for (int r = 0; r < 4; ++r) {
        int i = q + 4*r;
        float acc = E ? E[i*16 + j] : 0.f;
#pragma unroll
        for (int k = 0; k < 16; ++k) acc += A[k*16 + i] * bc[k];
        D[i*16 + j] = acc;
    }
}

// ---------------- Gauss-Jordan invert 16x16 (W: 16x32 augmented, stride 36) --
__device__ void gj_invert16(float* W, float* X, int tid) {
    int row = tid >> 2, cq = tid & 3;
#pragma unroll
    for (int c = 0; c < 4; ++c) {
        int cc = cq*4 + c;
        W[row*36 + 16 + cc] = (row == cc) ? 1.f : 0.f;
    }
    __syncthreads();
    for (int p = 0; p < 16; ++p) {
        float pinv = 1.f / W[p*36 + p];
        if (row == p) {
#pragma unroll
            for (int c = 0; c < 8; ++c) W[p*36 + cq*8 + c] *= pinv;
        }
        __syncthreads();
        float fac = W[row*36 + p];
        if (row != p) {
#pragma unroll
            for (int c = 0; c < 8; ++c) {
                int cc = cq*8 + c;
                W[row*36 + cc] -= fac * W[p*36 + cc];
            }
        }
        __syncthreads();
    }
    int q = tid >> 4, j = tid & 15;
#pragma unroll
    for (int r = 0; r < 4; ++r) {
        int i = q + 4*r;
        X[i*16 + j] = W[i*36 + 16 + j];
    }
}

// ---------------- element combine: E2 ∘ E1 (E1 first) — PROVEN R11/R12 ------
__device__ void el_combine(const float* A1, const float* C1, const float* J1,
                           const float* A2, const float* C2, const float* J2,
                           float* OA, float* OC, float* OJ,
                           float* W, float* T1, float* T2, float* T3, int tid) {
    int q = tid >> 4, j = tid & 15;
    {   // W left = I + C1*J2
        float bc[16];
#pragma unroll
        for (int k = 0; k < 16; ++k) bc[k] = J2[k*16 + j];
        float4 b0 = make_float4(bc[0],bc[1],bc[2],bc[3]);
        float4 b1 = make_float4(bc[4],bc[5],bc[6],bc[7]);
        float4 b2 = make_float4(bc[8],bc[9],bc[10],bc[11]);
        float4 b3 = make_float4(bc[12],bc[13],bc[14],bc[15]);
#pragma unroll
        for (int r = 0; r < 4; ++r) {
            int i = q + 4*r;
            const float4* Cr = (const float4*)(C1 + i*16);
            float acc = (i == j) ? 1.f : 0.f;
            acc += dot4(Cr[0], b0) + dot4(Cr[1], b1) + dot4(Cr[2], b2) + dot4(Cr[3], b3);
            W[i*36 + j] = acc;
        }
    }
    __syncthreads();
    gj_invert16(W, T1, tid);            // X -> T1
    __syncthreads();
    mm_nn(A2, T1, nullptr, T2, q, j);   // T = A2*X
    __syncthreads();
    mm_nn(T2, A1, nullptr, OA, q, j);   // A12
    mm_nn(T2, C1, nullptr, T3, q, j);   // U = T*C1
    __syncthreads();
    mm_nt(T3, A2, C2, OC, q, j);        // C12 = U*A2^T + C2
    mm_nn(J2, T1, nullptr, T2, q, j);   // W5 = J2*X
    __syncthreads();
    mm_tn(A1, T2, nullptr, T3, q, j);   // Y = A1^T*W5
    __syncthreads();
    mm_nn(T3, A1, J1, OJ, q, j);        // J12 = Y*A1 + J1
    __syncthreads();
}

// ---------------- K1: E^1 and 7 doublings -> DBL slots 0..7 -----------------
__global__ __launch_bounds__(64) void scan_init_kernel(
    const float* __restrict__ Fg, const float* __restrict__ Hg,
    const float* __restrict__ Qg, const float* __restrict__ Rg,
    float* __restrict__ ws)
{
    __shared__ float4 b1f[192], bof[192], btf[192];
    __shared__ float  bw[576];
    __shared__ float  sH[64], sRinv[16], sT4[64];
    float* eA1 = (float*)b1f;  float* eC1 = eA1 + 256;  float* eJ1 = eA1 + 512;
    float* OA  = (float*)bof;  float* OC  = OA + 256;   float* OJ  = OA + 512;
    float* T1  = (float*)btf;  float* T2  = T1 + 256;   float* T3  = T1 + 512;

    const int tid = threadIdx.x;
    const int q = tid >> 4, j = tid & 15;

    for (int u = tid; u < 256; u += 64) { eA1[u] = Fg[u]; eC1[u] = Qg[u]; }
    sH[tid] = Hg[tid];
    if (tid < 16) {     // Rinv via 4x4 cofactors
        int rr = tid >> 2, cc_ = tid & 3;
        int ra = (rr == 0) ? 1 : 0, rb = (rr <= 1) ? 2 : 1, rc = (rr <= 2) ? 3 : 2;
        const float4* Rg4 = (const float4*)Rg;
        float4 a = Rg4[ra], b = Rg4[rb], c = Rg4[rc], sm = Rg4[rr];
        float M0 = a.y*(b.z*c.w - b.w*c.z) - a.z*(b.y*c.w - b.w*c.y) + a.w*(b.y*c.z - b.z*c.y);
        float M1 = a.x*(b.z*c.w - b.w*c.z) - a.z*(b.x*c.w - b.w*c.x) + a.w*(b.x*c.z - b.z*c.x);
        float M2 = a.x*(b.y*c.w - b.w*c.y) - a.y*(b.x*c.w - b.w*c.x) + a.w*(b.x*c.y - b.y*c.x);
        float M3 = a.x*(b.y*c.z - b.z*c.y) - a.y*(b.x*c.z - b.z*c.x) + a.z*(b.x*c.y - b.y*c.x);
        float sg = (rr & 1) ? -1.f : 1.f;
        float c0 = sg*M0, c1 = -sg*M1, c2 = sg*M2, c3 = -sg*M3;
        float det = sm.x*c0 + sm.y*c1 + sm.z*c2 + sm.w*c3;
        float cofc = (cc_ == 0) ? c0 : ((cc_ == 1) ? c1 : ((cc_ == 2) ? c2 : c3));
        sRinv[cc_*4 + rr] = cofc / det;
    }
    __syncthreads();
    {   // T4 = Rinv * H  (4x16)
        int m = tid >> 4, j2 = tid & 15;
        float acc = 0.f;
#pragma unroll
        for (int n = 0; n < 4; ++n) acc += sRinv[m*4 + n] * sH[n*16 + j2];
        sT4[m*16 + j2] = acc;
    }
    __syncthreads();
#pragma unroll
    for (int r = 0; r < 4; ++r) {   // J = H^T * T4
        int i = q + 4*r;
        float acc = 0.f;
#pragma unroll
        for (int m = 0; m < 4; ++m) acc += sH[m*16 + i] * sT4[m*16 + j];
        eJ1[i*16 + j] = acc;
    }
    __syncthreads();
    // store slot 0 = E^1
    for (int u = tid; u < 256; u += 64) {
        ws[u] = eA1[u]; ws[256 + u] = eC1[u]; ws[512 + u] = eJ1[u];
    }
    __syncthreads();
    // doublings: slot d = E^{2^d}
    for (int d = 1; d <= 7; ++d) {
        el_combine(eA1, eC1, eJ1, eA1, eC1, eJ1, OA, OC, OJ, bw, T1, T2, T3, tid);
        int base = d*768;
        for (int u = tid; u < 256; u += 64) {
            eA1[u] = OA[u]; eC1[u] = OC[u]; eJ1[u] = OJ[u];
            ws[base + u] = OA[u]; ws[base + 256 + u] = OC[u]; ws[base + 512 + u] = OJ[u];
        }
        __syncthreads();
    }
}

// ---------------- K2: E^{16k}, k=1..15, via binary expansion ----------------
__global__ __launch_bounds__(64) void chain_kernel(float* __restrict__ ws)
{
    __shared__ float4 b1f[192], b2f[192], bof[192], btf[192];
    __shared__ float  bw[576];
    float* eA1 = (float*)b1f;  float* eC1 = eA1 + 256;  float* eJ1 = eA1 + 512;
    float* eA2 = (float*)b2f;  float* eC2 = eA2 + 256;  float* eJ2 = eA2 + 512;
    float* OA  = (float*)bof;  float* OC  = OA + 256;   float* OJ  = OA + 512;
    float* T1  = (float*)btf;  float* T2  = T1 + 256;   float* T3  = T1 + 512;

    const int tid = threadIdx.x;
    const int k = blockIdx.x + 1;      // 1..15
    bool have = false;
    for (int bit = 0; bit < 4; ++bit) {
        if (!((k >> bit) & 1)) continue;
        const float* src = ws + (4 + bit)*768;   // E^{16*2^bit}
        if (!have) {
            for (int u = tid; u < 768; u += 64) eA1[u] = src[u];
            have = true;
            __syncthreads();
        } else {
            for (int u = tid; u < 768; u += 64) eA2[u] = src[u];
            __syncthreads();
            el_combine(eA1, eC1, eJ1, eA2, eC2, eJ2, OA, OC, OJ, bw, T1, T2, T3, tid);
            for (int u = tid; u < 768; u += 64) eA1[u] = OA[u];
            __syncthreads();
        }
    }
    float* dst = ws + CHEOFF + (k - 1)*768;
    for (int u = tid; u < 768; u += 64) dst[u] = eA1[u];
}

// ---------------- K3: per-chunk riccati + operator accumulation -------------
// R13: W buffers zero-initialized -> all operator loops are STATIC and
// unrollable (A*0=0 keeps invalid rows zero); HW rows s>=k become exact
// zeros in ws, which lets K4 run a divergence-free unrolled inner loop.
__global__ __launch_bounds__(64) void chunkop_kernel(
    const float* __restrict__ Fg, const float* __restrict__ Hg,
    const float* __restrict__ Qg, const float* __restrict__ Rg,
    const float* __restrict__ sdg, float* __restrict__ ws)
{
    __shared__ float4 sF4[80], sP4[80], sA4[80], sAP4[80];
    __shared__ float4 sHP4[16], sV4[16], sB4[16], sS4[4];
    __shared__ float  sFd[256];
    __shared__ float4 btf[192], eEf[192];
    __shared__ float  bw[576];
    __shared__ float4 sGt4[2][64];
    __shared__ float4 sWt4[2][256];

    float* sF  = (float*)sF4;   float* sP  = (float*)sP4;
    float* sA  = (float*)sA4;   float* sAP = (float*)sAP4;
    float* sHP = (float*)sHP4;  float* sV  = (float*)sV4;
    float* sB  = (float*)sB4;   float* sS  = (float*)sS4;
    float* T1  = (float*)btf;   float* T2 = T1 + 256;  float* T3 = T1 + 512;
    float* eA  = (float*)eEf;   float* eC = eA + 256;  float* eJ = eA + 512;
    float* sGt0 = (float*)sGt4[0]; float* sGt1 = (float*)sGt4[1];
    float* sWt0 = (float*)sWt4[0]; float* sWt1 = (float*)sWt4[1];

    const int tid = threadIdx.x;
    const int q  = tid >> 4, j = tid & 15;
    const int bi = tid >> 2, bm = tid & 3;
    const int c  = blockIdx.x;               // chunk 0..15
    const int L  = (c == 15) ? 15 : 16;
    const int base = OPOFF + c*OPSZ;

    const float4* Fg4 = (const float4*)Fg;
    const float4* Hg4 = (const float4*)Hg;
    const float4* Rg4 = (const float4*)Rg;

    // stage F (stride 20 + dense)
    for (int u = tid; u < 256; u += 64) {
        sF[(u >> 4)*20 + (u & 15)] = Fg[u];
        sFd[u] = Fg[u];
    }
    // zero both W buffers (enables static loops) + HW k=0 row in ws
    for (int u = tid; u < 1024; u += 64) { sWt0[u] = 0.f; sWt1[u] = 0.f; }
    for (int u = tid; u < 256; u += 64) ws[base + HW_O + u] = 0.f;
    if (c > 0) {
        const float* src = ws + CHEOFF + (c - 1)*768;
        for (int u = tid; u < 768; u += 64) eA[u] = src[u];
    }

    // register preloads (R9-proven set)
    float4 zF[4][4], zFbi[4], zFj[4], zHq[4], zHn[4], zHm[4];
#pragma unroll
    for (int r = 0; r < 4; ++r)
#pragma unroll
        for (int f = 0; f < 4; ++f) zF[r][f] = Fg4[(q + 4*r)*4 + f];
#pragma unroll
    for (int f = 0; f < 4; ++f) {
        zFbi[f] = Fg4[bi*4 + f];
        zFj[f]  = Fg4[j*4 + f];
        zHq[f]  = Hg4[q*4 + f];
        zHn[f]  = Hg4[bm*4 + f];
        zHm[f]  = Hg4[((tid >> 2) & 3)*4 + f];
    }
    float zQ[4];
#pragma unroll
    for (int r = 0; r < 4; ++r) zQ[r] = Qg[(q + 4*r)*16 + j];
    float  zRs = Rg[tid & 15];
    float4 zR4[4];
#pragma unroll
    for (int m = 0; m < 4; ++m) zR4[m] = Rg4[m];
    float4 zHcjv = make_float4(Hg[j], Hg[16 + j], Hg[32 + j], Hg[48 + j]);
    float4 zFijv = make_float4(Fg[q*16 + j],     Fg[(q+4)*16 + j],
                               Fg[(q+8)*16 + j], Fg[(q+12)*16 + j]);
    float4 zSd2[4];
    float  sd2[16];
#pragma unroll
    for (int f = 0; f < 4; ++f) {
        float4 s = ((const float4*)sdg)[f];
        zSd2[f] = make_float4(s.x*s.x, s.y*s.y, s.z*s.z, s.w*s.w);
        sd2[f*4+0] = s.x*s.x; sd2[f*4+1] = s.y*s.y;
        sd2[f*4+2] = s.z*s.z; sd2[f*4+3] = s.w*s.w;
    }
    __syncthreads();

    // ---- P_start -> sP (stride 20) ----
    if (c == 0) {
#pragma unroll
        for (int r = 0; r < 4; ++r) {
            float acc = zQ[r];
#pragma unroll
            for (int f = 0; f < 4; ++f) {
                float4 a = zF[r][f], b = zFj[f], s = zSd2[f];
                acc += a.x*s.x*b.x + a.y*s.y*b.y + a.z*s.z*b.z + a.w*s.w*b.w;
            }
            sP[(q + 4*r)*20 + j] = acc;
        }
        __syncthreads();
    } else {
        float* pg = T2;   // dense P0 scratch
#pragma unroll
        for (int r = 0; r < 4; ++r) {
            int i = q + 4*r;
            float acc = Qg[i*16 + j];
#pragma unroll
            for (int k = 0; k < 16; ++k) acc += sFd[i*16 + k]*sd2[k]*sFd[j*16 + k];
            pg[i*16 + j] = acc;
        }
        __syncthreads();
        {   // W = I + P0*J
            float bc[16];
#pragma unroll
            for (int k = 0; k < 16; ++k) bc[k] = eJ[k*16 + j];
            float4 b0 = make_float4(bc[0],bc[1],bc[2],bc[3]);
            float4 b1 = make_float4(bc[4],bc[5],bc[6],bc[7]);
            float4 b2 = make_float4(bc[8],bc[9],bc[10],bc[11]);
            float4 b3 = make_float4(bc[12],bc[13],bc[14],bc[15]);
#pragma unroll
            for (int r = 0; r < 4; ++r) {
                int i = q + 4*r;
                const float4* Pr = (const float4*)(pg + i*16);
                float acc = (i == j) ? 1.f : 0.f;
                acc += dot4(Pr[0],b0) + dot4(Pr[1],b1) + dot4(Pr[2],b2) + dot4(Pr[3],b3);
                bw[i*36 + j] = acc;
            }
        }
        __syncthreads();
        gj_invert16(bw, T1, tid);           // X
        __syncthreads();
        mm_nn(T1, pg, nullptr, T3, q, j);   // G = X*P0
        __syncthreads();
#pragma unroll
        for (int r = 0; r < 4; ++r) {       // symmetrize -> T1
            int i = q + 4*r;
            T1[i*16 + j] = 0.5f*(T3[i*16 + j] + T3[j*16 + i]);
        }
        __syncthreads();
        mm_nn(eA, T1, nullptr, T3, q, j);   // U = A*G
        __syncthreads();
        mm_nt(T3, eA, eC, T2, q, j);        // P = U*A^T + C
        __syncthreads();
#pragma unroll
        for (int r = 0; r < 4; ++r) {
            int i = q + 4*r;
            sP[i*20 + j] = T2[i*16 + j];
        }
        __syncthreads();
    }

    // ---- init operators: Gt[0] = I ; HG_0 = H ----
#pragma unroll
    for (int r = 0; r < 4; ++r) {
        int i = q + 4*r;
        sGt0[j*16 + i] = (i == j) ? 1.f : 0.f;
    }
    ws[base + 0*64 + q*16 + j] = Hg[q*16 + j];
    __syncthreads();

    int cur = 0;
    for (int k = 0; k < L; ++k) {
        float* Gn = cur ? sGt0 : sGt1;
        float* Wn = cur ? sWt0 : sWt1;
        float4* Gc4 = cur ? sGt4[1] : sGt4[0];
        float4* Gn4 = cur ? sGt4[0] : sGt4[1];
        float4* Wn4 = cur ? sWt4[0] : sWt4[1];
        float4* Wc4 = cur ? sWt4[1] : sWt4[0];

        // ===== Riccati step (R9-proven) =====
        float4 zP[4];
#pragma unroll
        for (int f = 0; f < 4; ++f) zP[f] = sP4[j*5 + f];
        float tf[4], hp = 0.f;
#pragma unroll
        for (int r = 0; r < 4; ++r) {
            float acc = 0.f;
#pragma unroll
            for (int f = 0; f < 4; ++f) acc += dot4(zF[r][f], zP[f]);
            tf[r] = acc;
        }
#pragma unroll
        for (int f = 0; f < 4; ++f) hp += dot4(zHq[f], zP[f]);
        sHP[q*16 + j] = hp;
        __syncthreads();
        {
            float acc = 0.f;
#pragma unroll
            for (int f = 0; f < 4; ++f) acc += dot4(zFbi[f], sHP4[bm*4 + f]);
            sV[bi*4 + bm] = acc;
        }
        if (tid < 16) {
            float acc = zRs;
#pragma unroll
            for (int f = 0; f < 4; ++f) acc += dot4(sHP4[(tid >> 2)*4 + f], zHn[f]);
            sS[tid] = acc;
        }
        __syncthreads();
        {
            int ra = (bm == 0) ? 1 : 0;
            int rb = (bm <= 1) ? 2 : 1;
            int rc = (bm <= 2) ? 3 : 2;
            float4 a = sS4[ra], b = sS4[rb], cc = sS4[rc], sm = sS4[bm];
            float M0 = a.y*(b.z*cc.w - b.w*cc.z) - a.z*(b.y*cc.w - b.w*cc.y) + a.w*(b.y*cc.z - b.z*cc.y);
            float M1 = a.x*(b.z*cc.w - b.w*cc.z) - a.z*(b.x*cc.w - b.w*cc.x) + a.w*(b.x*cc.z - b.z*cc.x);
            float M2 = a.x*(b.y*cc.w - b.w*cc.y) - a.y*(b.x*cc.w - b.w*cc.x) + a.w*(b.x*cc.y - b.y*cc.x);
            float M3 = a.x*(b.y*cc.z - b.z*cc.y) - a.y*(b.x*cc.z - b.z*cc.x) + a.z*(b.x*cc.y - b.y*cc.x);
            float sg = (bm & 1) ? -1.f : 1.f;
            float c0 = sg*M0, c1 = -sg*M1, c2 = sg*M2, c3 = -sg*M3;
            float det = sm.x*c0 + sm.y*c1 + sm.z*c2 + sm.w*c3;
            float4 vv = sV4[bi];
            sB[tid] = (vv.x*c0 + vv.y*c1 + vv.z*c2 + vv.w*c3) / det;
        }
        __syncthreads();
        float4 bq[4], rbtv;
        {
            float4 hpcv = make_float4(sHP[j], sHP[16 + j], sHP[32 + j], sHP[48 + j]);
            float4 bj = sB4[j];
#pragma unroll
            for (int r = 0; r < 4; ++r) {
                int i = q + 4*r;
                bq[r] = sB4[i];
                sA[i*20 + j]  = ((const float*)&zFijv)[r] - dot4(bq[r], zHcjv);
                sAP[i*20 + j] = tf[r] - dot4(bq[r], hpcv);
            }
            rbtv = make_float4(dot4(zR4[0], bj), dot4(zR4[1], bj),
                               dot4(zR4[2], bj), dot4(zR4[3], bj));
        }
        __syncthreads();
        float4 zA[4];
#pragma unroll
        for (int f = 0; f < 4; ++f) zA[f] = sA4[j*5 + f];
#pragma unroll
        for (int r = 0; r < 4; ++r) {
            int i = q + 4*r;
            float acc = zQ[r] + dot4(bq[r], rbtv);
#pragma unroll
            for (int f = 0; f < 4; ++f) acc += dot4(sAP4[i*5 + f], zA[f]);
            sP[i*20 + j] = acc;
        }
        __syncthreads();   // sP done; sA/sB stable

        // ===== operator updates (A_k in sA, B_k in sB) — STATIC loops =====
        {
            float4 gtj[4];
#pragma unroll
            for (int f = 0; f < 4; ++f) gtj[f] = Gc4[j*4 + f];
#pragma unroll
            for (int r = 0; r < 4; ++r) {
                int i = q + 4*r;
                const float4* Ar = (const float4*)(sA + i*20);
                Gn[j*16 + i] = dot4(Ar[0], gtj[0]) + dot4(Ar[1], gtj[1])
                             + dot4(Ar[2], gtj[2]) + dot4(Ar[3], gtj[3]);
            }
        }
        {
            int i2 = tid >> 2, n = tid & 3;
            const float4* Ai = (const float4*)(sA + i2*20);
            float4 a0 = Ai[0], a1 = Ai[1], a2 = Ai[2], a3 = Ai[3];
#pragma unroll
            for (int s = 0; s < 16; ++s) {   // rows s>=k are 0 -> stay 0
                float4 w0 = Wc4[s*16 + n*4 + 0], w1 = Wc4[s*16 + n*4 + 1],
                       w2 = Wc4[s*16 + n*4 + 2], w3 = Wc4[s*16 + n*4 + 3];
                Wn[s*64 + n*16 + i2] = dot4(a0,w0) + dot4(a1,w1) + dot4(a2,w2) + dot4(a3,w3);
            }
            Wn[k*64 + n*16 + i2] = sB[i2*4 + n];
        }
        __syncthreads();

        // projections for k1 = k+1 — STATIC s loop (zeros propagate)
        int k1 = k + 1;
        if (k1 <= 15) {
            {
                float4 g0 = Gn4[j*4 + 0], g1 = Gn4[j*4 + 1],
                       g2 = Gn4[j*4 + 2], g3 = Gn4[j*4 + 3];
                ws[base + k1*64 + q*16 + j] =
                    dot4(zHq[0],g0) + dot4(zHq[1],g1) + dot4(zHq[2],g2) + dot4(zHq[3],g3);
            }
            {
                int so = tid >> 4, m2 = (tid >> 2) & 3, n2 = tid & 3;
#pragma unroll
                for (int si = 0; si < 4; ++si) {
                    int s = so + 4*si;
                    float4 w0 = Wn4[s*16 + n2*4 + 0], w1 = Wn4[s*16 + n2*4 + 1],
                           w2 = Wn4[s*16 + n2*4 + 2], w3 = Wn4[s*16 + n2*4 + 3];
                    ws[base + HW_O + k1*256 + s*16 + m2*4 + n2] =
                        dot4(zHm[0],w0) + dot4(zHm[1],w1) + dot4(zHm[2],w2) + dot4(zHm[3],w3);
                }
            }
        }
        cur ^= 1;
        __syncthreads();
    }

    // ---- GL/WL for c<15 (final G = Gt[cur], W = Wt[cur]) ----
    if (c < 15) {
        float* Gc = cur ? sGt1 : sGt0;
        float* Wc = cur ? sWt1 : sWt0;
#pragma unroll
        for (int r = 0; r < 4; ++r) {
            int i = q + 4*r;
            ws[base + GL_O + i*16 + j] = Gc[j*16 + i];
        }
        int i2 = tid >> 2, n = tid & 3;
#pragma unroll
        for (int s = 0; s < 16; ++s)
            ws[base + WL_O + s*64 + i2*4 + n] = Wc[s*64 + n*16 + i2];
    }
}

// ---------------- K4: chunked affine filter (R13: static unrolled loops) ----
// 256 blocks x 64 threads, 4 batches/block. LDS pack is RESTRIDED during
// staging (HG stride 17/k, HW stride 65/k, obs stride 17/g) to break the
// 4-8-way bank conflicts of the dense layout. Inner s-loop is a fixed
// 15-iteration unroll (HW rows s>=k are exact zeros) -> no divergence,
// all LDS reads pipeline at throughput.
__global__ __launch_bounds__(64) void cfilter_kernel(
    const float* __restrict__ obs, const float* __restrict__ Fg,
    const float* __restrict__ x0g, const float* __restrict__ ws,
    float* __restrict__ out)
{
    __shared__ float4 sPk4[1632];     // HG[0,272) HW[272,1312) GL[1312,1376) WL[1376,1632)
    __shared__ float4 sObs4v[68];     // [g][s], stride 17
    __shared__ float4 zLDS4[16];      // [g][i] as 4 float4 per g
    __shared__ float4 sOutF[64];      // [g][k] float4 over m
    float* zLDS = (float*)zLDS4;
    float* sOut = (float*)sOutF;

    const int tid = threadIdx.x;
    const int g = tid >> 4, i = tid & 15;

    // z0 = F x0
    {
        const float4* Fg4 = (const float4*)Fg;
        const float4* x04 = (const float4*)x0g;
        float acc = 0.f;
#pragma unroll
        for (int f = 0; f < 4; ++f) acc += dot4(Fg4[i*4 + f], x04[f]);
        zLDS[g*16 + i] = acc;
    }

    const float4* wsf4 = (const float4*)ws;
    const float4* obs4 = (const float4*)obs;
    float4* out4 = (float4*)out;

    const int m  = i & 3;
    const int kb = i >> 2;

    for (int c = 0; c < 16; ++c) {
        const int t0 = 16*c;
        const int L  = (c == 15) ? 15 : 16;
        __syncthreads();   // zLDS write + prev sOut flush complete
        {   // stage pack with restriding
            const float4* src = wsf4 + (OPOFF + c*OPSZ)/4;
            for (int u = tid; u < 1600; u += 64) {
                int dst;
                if (u < 256)       dst = (u >> 4)*17 + (u & 15);
                else if (u < 1280) { int v = u - 256; dst = 272 + (v >> 6)*65 + (v & 63); }
                else if (u < 1344) dst = 1312 + (u - 1280);
                else               dst = 1376 + (u - 1344);
                sPk4[dst] = src[u];
            }
        }
        {   // obs: full 64-slot space, ss<L guard (R8 lesson)
            int ss = tid & 15, gg = tid >> 4;
            if (ss < L)
                sObs4v[gg*17 + ss] = obs4[(blockIdx.x*4 + gg) * NT + t0 + ss];
        }
        __syncthreads();
        float4 zv[4];
#pragma unroll
        for (int f = 0; f < 4; ++f) zv[f] = zLDS4[g*4 + f];
        // 4 outputs per lane: k = kb + 4r, col m — fully unrolled, no divergence
#pragma unroll
        for (int r = 0; r < 4; ++r) {
            int k = kb + 4*r;
            const float4* hg = &sPk4[k*17 + m*4];
            float v = dot4(hg[0],zv[0]) + dot4(hg[1],zv[1])
                    + dot4(hg[2],zv[2]) + dot4(hg[3],zv[3]);
#pragma unroll
            for (int s = 0; s < 15; ++s) {   // HW[k][s]=0 for s>=k
                float4 hw = sPk4[272 + k*65 + s*4 + m];
                v += dot4(hw, sObs4v[g*17 + s]);
            }
            sOut[g*64 + k*4 + m] = v;
        }
        // z advance (c<15)
        float zn = 0.f;
        if (c < 15) {
            const float4* gl = &sPk4[1312 + i*4];
            zn = dot4(gl[0],zv[0]) + dot4(gl[1],zv[1])
               + dot4(gl[2],zv[2]) + dot4(gl[3],zv[3]);
#pragma unroll
            for (int s = 0; s < 16; ++s) {
                float4 wl = sPk4[1376 + s*16 + i];
                zn += dot4(wl, sObs4v[g*17 + s]);
            }
        }
        __syncthreads();   // sOut complete
        {   // flush 64 float4: (gg, kk)
            int gg = tid >> 4, kk = tid & 15;
            out4[(blockIdx.x*4 + gg) * NT + t0 + kk] = sOutF[gg*16 + kk];
        }
        if (c < 15) zLDS[g*16 + i] = zn;
    }
}

// ================= FALLBACK: proven R9 fused kernel (242 us) =================
__global__ __launch_bounds__(64) void kf_block_kernel(
    const float* __restrict__ obs, const float* __restrict__ Fg,
    const float* __restrict__ Hg,  const float* __restrict__ Qg,
    const float* __restrict__ Rg,  const float* __restrict__ x0g,
    const float* __restrict__ sdg, float* __restrict__ out)
{
    __shared__ float4 sF4[80], sP4[80], sA4[80], sAP4[80];
    __shared__ float4 sHP4[16], sV4[16], sB4[16], sS4[4];
    __shared__ float  sH[64], sZ[16];
    __shared__ float4 sObs4[1024], sOut4v[1024];

    float* sF  = (float*)sF4;   float* sP  = (float*)sP4;
    float* sA  = (float*)sA4;   float* sAP = (float*)sAP4;
    float* sHP = (float*)sHP4;  float* sV  = (float*)sV4;
    float* sB  = (float*)sB4;   float* sS  = (float*)sS4;
    float* sOut = (float*)sOut4v;

    const int tid = threadIdx.x;
    const int q  = tid >> 4, j = tid & 15;
    const int bi = tid >> 2, bm = tid & 3;
    const int gbase = tid & 48;

    const float4* Fg4 = (const float4*)Fg;
    const float4* Hg4 = (const float4*)Hg;
    const float4* Rg4 = (const float4*)Rg;
    const float4* obs4g = (const float4*)obs;

    for (int u = tid; u < 256; u += 64) sF[(u >> 4) * 20 + (u & 15)] = Fg[u];
    sH[tid] = Hg[tid];
    for (int u = tid; u < 1024; u += 64)
        sObs4[u] = obs4g[(blockIdx.x * 4 + (u >> 8)) * NT + (u & 255)];

    float4 zF[4][4], zFbi[4], zFj[4], zHq[4], zHn[4], zHrow4[4];
#pragma unroll
    for (int r = 0; r < 4; ++r)
#pragma unroll
        for (int f = 0; f < 4; ++f) zF[r][f] = Fg4[(q + 4*r)*4 + f];
#pragma unroll
    for (int f = 0; f < 4; ++f) {
        zFbi[f]   = Fg4[bi*4 + f];
        zFj[f]    = Fg4[j*4 + f];
        zHq[f]    = Hg4[q*4 + f];
        zHn[f]    = Hg4[bm*4 + f];
        zHrow4[f] = Hg4[(j & 3)*4 + f];
    }
    float hr[16] = {zHrow4[0].x,zHrow4[0].y,zHrow4[0].z,zHrow4[0].w,
                    zHrow4[1].x,zHrow4[1].y,zHrow4[1].z,zHrow4[1].w,
                    zHrow4[2].x,zHrow4[2].y,zHrow4[2].z,zHrow4[2].w,
                    zHrow4[3].x,zHrow4[3].y,zHrow4[3].z,zHrow4[3].w};
    float zQ[4];
#pragma unroll
    for (int r = 0; r < 4; ++r) zQ[r] = Qg[(q + 4*r)*16 + j];
    float  zRs = Rg[tid & 15];
    float4 zR4[4];
#pragma unroll
    for (int m = 0; m < 4; ++m) zR4[m] = Rg4[m];
    float4 zHcjv = make_float4(Hg[j], Hg[16 + j], Hg[32 + j], Hg[48 + j]);
    float4 zFijv = make_float4(Fg[q*16 + j],     Fg[(q+4)*16 + j],
                               Fg[(q+8)*16 + j], Fg[(q+12)*16 + j]);
    float4 zSd2[4];
#pragma unroll
    for (int f = 0; f < 4; ++f) {
        float4 s = ((const float4*)sdg)[f];
        zSd2[f] = make_float4(s.x*s.x, s.y*s.y, s.z*s.z, s.w*s.w);
    }
    __syncthreads();

#pragma unroll
    for (int r = 0; r < 4; ++r) {
        float acc = zQ[r];
#pragma unroll
        for (int f = 0; f < 4; ++f) {
            float4 a = zF[r][f], b = zFj[f], s = zSd2[f];
            acc += a.x*s.x*b.x + a.y*s.y*b.y + a.z*s.z*b.z + a.w*s.w*b.w;
        }
        sP[(q + 4*r)*20 + j] = acc;
    }
    if (tid < 16) {
        float acc = 0.f;
#pragma unroll
        for (int f = 0; f < 4; ++f) {
            float4 fr = ((float4*)(sF + tid*20))[f];
            float4 xv = ((const float4*)x0g)[f];
            acc += dot4(fr, xv);
        }
        sZ[tid] = acc;
    }
    __syncthreads();
    float zr = sZ[j];

    for (int t = 0; t < NSTEP; ++t) {
        float4 zP[4];
#pragma unroll
        for (int f = 0; f < 4; ++f) zP[f] = sP4[j*5 + f];
        float tf[4], hp = 0.f;
#pragma unroll
        for (int r = 0; r < 4; ++r) {
            float acc = 0.f;
#pragma unroll
            for (int f = 0; f < 4; ++f) acc += dot4(zF[r][f], zP[f]);
            tf[r] = acc;
        }
#pragma unroll
        for (int f = 0; f < 4; ++f) hp += dot4(zHq[f], zP[f]);
        sHP[q*16 + j] = hp;
        __syncthreads();
        {
            float acc = 0.f;
#pragma unroll
            for (int f = 0; f < 4; ++f) acc += dot4(zFbi[f], sHP4[bm*4 + f]);
            sV[bi*4 + bm] = acc;
        }
        if (tid < 16) {
            float acc = zRs;
#pragma unroll
            for (int f = 0; f < 4; ++f) acc += dot4(sHP4[(tid >> 2)*4 + f], zHn[f]);
            sS[tid] = acc;
        }
        __syncthreads();
        {
            int ra = (bm == 0) ? 1 : 0;
            int rb = (bm <= 1) ? 2 : 1;
            int rc = (bm <= 2) ? 3 : 2;
            float4 a = sS4[ra], b = sS4[rb], c = sS4[rc], sm = sS4[bm];
            float M0 = a.y*(b.z*c.w - b.w*c.z) - a.z*(b.y*c.w - b.w*c.y) + a.w*(b.y*c.z - b.z*c.y);
            float M1 = a.x*(b.z*c.w - b.w*c.z) - a.z*(b.x*c.w - b.w*c.x) + a.w*(b.x*c.z - b.z*c.x);
            float M2 = a.x*(b.y*c.w - b.w*c.y) - a.y*(b.x*c.w - b.w*c.x) + a.w*(b.x*c.y - b.y*c.x);
            float M3 = a.x*(b.y*c.z - b.z*c.y) - a.y*(b.x*c.z - b.z*c.x) + a.z*(b.x*c.y - b.y*c.x);
            float sg = (bm & 1) ? -1.f : 1.f;
            float c0 = sg*M0, c1 = -sg*M1, c2 = sg*M2, c3 = -sg*M3;
            float det = sm.x*c0 + sm.y*c1 + sm.z*c2 + sm.w*c3;
            float4 vv = sV4[bi];
            sB[tid] = (vv.x*c0 + vv.y*c1 + vv.z*c2 + vv.w*c3) / det;
        }
        __syncthreads();
        float4 bq[4], rbtv;
        {
            float4 hpcv = make_float4(sHP[j], sHP[16 + j], sHP[32 + j], sHP[48 + j]);
            float4 bj = sB4[j];
#pragma unroll
            for (int r = 0; r < 4; ++r) {
                int i = q + 4*r;
                bq[r] = sB4[i];
                sA[i*20 + j]  = ((const float*)&zFijv)[r] - dot4(bq[r], zHcjv);
                sAP[i*20 + j] = tf[r] - dot4(bq[r], hpcv);
            }
            rbtv = make_float4(dot4(zR4[0], bj), dot4(zR4[1], bj),
                               dot4(zR4[2], bj), dot4(zR4[3], bj));
        }
        __syncthreads();
        float4 zA[4];
#pragma unroll
        for (int f = 0; f < 4; ++f) zA[f] = sA4[j*5 + f];
#pragma unroll
        for (int r = 0; r < 4; ++r) {
            int i = q + 4*r;
            float acc = zQ[r] + dot4(bq[r], rbtv);
#pragma unroll
            for (int f = 0; f < 4; ++f) acc += dot4(sAP4[i*5 + f], zA[f]);
            sP[i*20 + j] = acc;
        }
        {
            float arr[16] = {zA[0].x,zA[0].y,zA[0].z,zA[0].w,
                             zA[1].x,zA[1].y,zA[1].z,zA[1].w,
                             zA[2].x,zA[2].y,zA[2].z,zA[2].w,
                             zA[3].x,zA[3].y,zA[3].z,zA[3].w};
            float4 bb = sB4[j];
            float4 oo = sObs4[q*256 + t];
            float o = 0.f, zn = dot4(bb, oo);
#pragma unroll
            for (int k = 0; k < 16; ++k) {
                float zk = __shfl(zr, gbase + k);
                o  = fmaf(hr[k],  zk, o);
                zn = fmaf(arr[k], zk, zn);
            }
            if (j < 4) sOut[(q*256 + t)*4 + j] = o;
            zr = zn;
        }
        __syncthreads();
    }
    {
        float o = 0.f;
#pragma unroll
        for (int k = 0; k < 16; ++k) {
            float zk = __shfl(zr, gbase + k);
            o = fmaf(hr[k], zk, o);
        }
        if (j < 4) sOut[(q*256 + 255)*4 + j] = o;
    }
    __syncthreads();
    float4* out4 = (float4*)out;
    for (int u = tid; u < 1024; u += 64)
        out4[(blockIdx.x * 4 + (u >> 8)) * NT + (u & 255)] = sOut4v[u];
}

extern "C" void kernel_launch(void* const* d_in, const int* in_sizes, int n_in,
                              void* d_out, int out_size, void* d_ws, size_t ws_size,
                              hipStream_t stream) {
    const float* obs = (const float*)d_in[0];   // [B,T,M]
    const float* F   = (const float*)d_in[1];   // [S,S]
    const float* H   = (const float*)d_in[2];   // [M,S]
    const float* Q   = (const float*)d_in[3];   // [S,S]
    const float* R   = (const float*)d_in[4];   // [M,M]
    const float* x0  = (const float*)d_in[5];   // [S]
    const float* sd  = (const float*)d_in[6];   // [S]
    float* ws  = (float*)d_ws;
    float* out = (float*)d_out;

    if (ws_size < NEED_WS_BYTES) {
        hipLaunchKernelGGL(kf_block_kernel, dim3(256), dim3(64), 0, stream,
                           obs, F, H, Q, R, x0, sd, out);
        return;
    }
    hipLaunchKernelGGL(scan_init_kernel, dim3(1),   dim3(64), 0, stream, F, H, Q, R, ws);
    hipLaunchKernelGGL(chain_kernel,     dim3(15),  dim3(64), 0, stream, ws);
    hipLaunchKernelGGL(chunkop_kernel,   dim3(16),  dim3(64), 0, stream, F, H, Q, R, sd, ws);
    hipLaunchKernelGGL(cfilter_kernel,   dim3(256), dim3(64), 0, stream, obs, F, x0, ws, out);
}

// Round 14
// 366.568 us; speedup vs baseline: 1.2503x; 1.2503x over previous
//
#include <hip/hip_runtime.h>

// B=1024 groups, T=256 steps, S=16 states, M=4 measurements
#define NT 256
#define NSTEP 255
// ws layout (floats):
//  [0 .. 6144)       8 doubling elements E^{2^d}, d=0..7, 768 floats each (A,C,J)
//  [17664 .. 120064) 16 chunk operator packs, 6400 floats each:
//      +0    HG  [k][m][j]        16*4*16 = 1024
//      +1024 HW  [k][s][m][n]     16*16*16 = 4096  (zero for s>=k)
//      +5120 GL  [i][j]           256
//      +5376 WL  [s][i][n]        16*16*4 = 1024
#define OPOFF  17664
#define OPSZ   6400
#define HW_O   1024
#define GL_O   5120
#define WL_O   5376
#define NEED_WS_BYTES 500000UL

__device__ __forceinline__ float dot4(float4 a, float4 b) {
    return a.x*b.x + a.y*b.y + a.z*b.z + a.w*b.w;
}

// ---------------- 16x16 matmul helpers (lane (q,j) owns rows q+4r, col j) ----
__device__ __forceinline__ void mm_nn(const float* A, const float* B,
                                      const float* E, float* D, int q, int j) {
    float bc[16];
#pragma unroll
    for (int k = 0; k < 16; ++k) bc[k] = B[k*16 + j];
    float4 b0 = make_float4(bc[0],bc[1],bc[2],bc[3]);
    float4 b1 = make_float4(bc[4],bc[5],bc[6],bc[7]);
    float4 b2 = make_float4(bc[8],bc[9],bc[10],bc[11]);
    float4 b3 = make_float4(bc[12],bc[13],bc[14],bc[15]);
#pragma unroll
    for (int r = 0; r < 4; ++r) {
        int i = q + 4*r;
        const float4* Ar = (const float4*)(A + i*16);
        float acc = E ? E[i*16 + j] : 0.f;
        acc += dot4(Ar[0], b0) + dot4(Ar[1], b1) + dot4(Ar[2], b2) + dot4(Ar[3], b3);
        D[i*16 + j] = acc;
    }
}
__device__ __forceinline__ void mm_nt(const float* A, const float* B,
                                      const float* E, float* D, int q, int j) {
    const float4* Bj = (const float4*)(B + j*16);
    float4 c0 = Bj[0], c1 = Bj[1], c2 = Bj[2], c3 = Bj[3];
#pragma unroll
    for (int r = 0; r < 4; ++r) {
        int i = q + 4*r;
        const float4* Ar = (const float4*)(A + i*16);
        float acc = E ? E[i*16 + j] : 0.f;
        acc += dot4(Ar[0], c0) + dot4(Ar[1], c1) + dot4(Ar[2], c2) + dot4(Ar[3], c3);
        D[i*16 + j] = acc;
    }
}
__device__ __forceinline__ void mm_tn(const float* A, const float* B,
                                      const float* E, float* D, int q, int j) {
    float bc[16];
#pragma unroll
    for (int k = 0; k < 16; ++k) bc[k] = B[k*16 + j];
#pragma unroll
    for (int r = 0; r < 4; ++r) {
        int i = q + 4*r;
        float acc = E ? E[i*16 + j] : 0.f;
#pragma unroll
        for (int k = 0; k < 16; ++k) acc += A[k*16 + i] * bc[k];
        D[i*16 + j] = acc;
    }
}

// ---------------- Gauss-Jordan invert 16x16 (W: 16x32 augmented, stride 36) --
__device__ void gj_invert16(float* W, float* X, int tid) {
    int row = tid >> 2, cq = tid & 3;
#pragma unroll
    for (int c = 0; c < 4; ++c) {
        int cc = cq*4 + c;
        W[row*36 + 16 + cc] = (row == cc) ? 1.f : 0.f;
    }
    __syncthreads();
    for (int p = 0; p < 16; ++p) {
        float pinv = 1.f / W[p*36 + p];
        if (row == p) {
#pragma unroll
            for (int c = 0; c < 8; ++c) W[p*36 + cq*8 + c] *= pinv;
        }
        __syncthreads();
        float fac = W[row*36 + p];
        if (row != p) {
#pragma unroll
            for (int c = 0; c < 8; ++c) {
                int cc = cq*8 + c;
                W[row*36 + cc] -= fac * W[p*36 + cc];
            }
        }
        __syncthreads();
    }
    int q = tid >> 4, j = tid & 15;
#pragma unroll
    for (int r = 0; r < 4; ++r) {
        int i = q + 4*r;
        X[i*16 + j] = W[i*36 + 16 + j];
    }
}

// ---------------- element combine: E2 ∘ E1 (E1 first) — PROVEN R11-R13 ------
__device__ void el_combine(const float* A1, const float* C1, const float* J1,
                           const float* A2, const float* C2, const float* J2,
                           float* OA, float* OC, float* OJ,
                           float* W, float* T1, float* T2, float* T3, int tid) {
    int q = tid >> 4, j = tid & 15;
    {   // W left = I + C1*J2
        float bc[16];
#pragma unroll
        for (int k = 0; k < 16; ++k) bc[k] = J2[k*16 + j];
        float4 b0 = make_float4(bc[0],bc[1],bc[2],bc[3]);
        float4 b1 = make_float4(bc[4],bc[5],bc[6],bc[7]);
        float4 b2 = make_float4(bc[8],bc[9],bc[10],bc[11]);
        float4 b3 = make_float4(bc[12],bc[13],bc[14],bc[15]);
#pragma unroll
        for (int r = 0; r < 4; ++r) {
            int i = q + 4*r;
            const float4* Cr = (const float4*)(C1 + i*16);
            float acc = (i == j) ? 1.f : 0.f;
            acc += dot4(Cr[0], b0) + dot4(Cr[1], b1) + dot4(Cr[2], b2) + dot4(Cr[3], b3);
            W[i*36 + j] = acc;
        }
    }
    __syncthreads();
    gj_invert16(W, T1, tid);            // X -> T1
    __syncthreads();
    mm_nn(A2, T1, nullptr, T2, q, j);   // T = A2*X
    __syncthreads();
    mm_nn(T2, A1, nullptr, OA, q, j);   // A12
    mm_nn(T2, C1, nullptr, T3, q, j);   // U = T*C1
    __syncthreads();
    mm_nt(T3, A2, C2, OC, q, j);        // C12 = U*A2^T + C2
    mm_nn(J2, T1, nullptr, T2, q, j);   // W5 = J2*X
    __syncthreads();
    mm_tn(A1, T2, nullptr, T3, q, j);   // Y = A1^T*W5
    __syncthreads();
    mm_nn(T3, A1, J1, OJ, q, j);        // J12 = Y*A1 + J1
    __syncthreads();
}

// ---------------- K1: E^1 and 7 doublings -> DBL slots 0..7 (PROVEN) --------
__global__ __launch_bounds__(64) void scan_init_kernel(
    const float* __restrict__ Fg, const float* __restrict__ Hg,
    const float* __restrict__ Qg, const float* __restrict__ Rg,
    float* __restrict__ ws)
{
    __shared__ float4 b1f[192], bof[192], btf[192];
    __shared__ float  bw[576];
    __shared__ float  sH[64], sRinv[16], sT4[64];
    float* eA1 = (float*)b1f;  float* eC1 = eA1 + 256;  float* eJ1 = eA1 + 512;
    float* OA  = (float*)bof;  float* OC  = OA + 256;   float* OJ  = OA + 512;
    float* T1  = (float*)btf;  float* T2  = T1 + 256;   float* T3  = T1 + 512;

    const int tid = threadIdx.x;
    const int q = tid >> 4, j = tid & 15;

    for (int u = tid; u < 256; u += 64) { eA1[u] = Fg[u]; eC1[u] = Qg[u]; }
    sH[tid] = Hg[tid];
    if (tid < 16) {     // Rinv via 4x4 cofactors
        int rr = tid >> 2, cc_ = tid & 3;
        int ra = (rr == 0) ? 1 : 0, rb = (rr <= 1) ? 2 : 1, rc = (rr <= 2) ? 3 : 2;
        const float4* Rg4 = (const float4*)Rg;
        float4 a = Rg4[ra], b = Rg4[rb], c = Rg4[rc], sm = Rg4[rr];
        float M0 = a.y*(b.z*c.w - b.w*c.z) - a.z*(b.y*c.w - b.w*c.y) + a.w*(b.y*c.z - b.z*c.y);
        float M1 = a.x*(b.z*c.w - b.w*c.z) - a.z*(b.x*c.w - b.w*c.x) + a.w*(b.x*c.z - b.z*c.x);
        float M2 = a.x*(b.y*c.w - b.w*c.y) - a.y*(b.x*c.w - b.w*c.x) + a.w*(b.x*c.y - b.y*c.x);
        float M3 = a.x*(b.y*c.z - b.z*c.y) - a.y*(b.x*c.z - b.z*c.x) + a.z*(b.x*c.y - b.y*c.x);
        float sg = (rr & 1) ? -1.f : 1.f;
        float c0 = sg*M0, c1 = -sg*M1, c2 = sg*M2, c3 = -sg*M3;
        float det = sm.x*c0 + sm.y*c1 + sm.z*c2 + sm.w*c3;
        float cofc = (cc_ == 0) ? c0 : ((cc_ == 1) ? c1 : ((cc_ == 2) ? c2 : c3));
        sRinv[cc_*4 + rr] = cofc / det;
    }
    __syncthreads();
    {   // T4 = Rinv * H  (4x16)
        int m = tid >> 4, j2 = tid & 15;
        float acc = 0.f;
#pragma unroll
        for (int n = 0; n < 4; ++n) acc += sRinv[m*4 + n] * sH[n*16 + j2];
        sT4[m*16 + j2] = acc;
    }
    __syncthreads();
#pragma unroll
    for (int r = 0; r < 4; ++r) {   // J = H^T * T4
        int i = q + 4*r;
        float acc = 0.f;
#pragma unroll
        for (int m = 0; m < 4; ++m) acc += sH[m*16 + i] * sT4[m*16 + j];
        eJ1[i*16 + j] = acc;
    }
    __syncthreads();
    for (int u = tid; u < 256; u += 64) {
        ws[u] = eA1[u]; ws[256 + u] = eC1[u]; ws[512 + u] = eJ1[u];
    }
    __syncthreads();
    for (int d = 1; d <= 7; ++d) {
        el_combine(eA1, eC1, eJ1, eA1, eC1, eJ1, OA, OC, OJ, bw, T1, T2, T3, tid);
        int base = d*768;
        for (int u = tid; u < 256; u += 64) {
            eA1[u] = OA[u]; eC1[u] = OC[u]; eJ1[u] = OJ[u];
            ws[base + u] = OA[u]; ws[base + 256 + u] = OC[u]; ws[base + 512 + u] = OJ[u];
        }
        __syncthreads();
    }
}

// ---------------- K2: per-chunk riccati + operator accumulation -------------
// R14: chain merged in — block c builds its own E^{16c} from the doubling
// table (<=3 in-block el_combines). Rest is R13's proven code (W buffers
// zero-padded -> static loops; HW rows s>=k exact zeros).
__global__ __launch_bounds__(64) void chunkop_kernel(
    const float* __restrict__ Fg, const float* __restrict__ Hg,
    const float* __restrict__ Qg, const float* __restrict__ Rg,
    const float* __restrict__ sdg, float* __restrict__ ws)
{
    __shared__ float4 sF4[80], sP4[80], sA4[80], sAP4[80];
    __shared__ float4 sHP4[16], sV4[16], sB4[16], sS4[4];
    __shared__ float  sFd[256];
    __shared__ float4 btf[192], eEf[192], e2f[192], eof[192];
    __shared__ float  bw[576];
    __shared__ float4 sGt4[2][64];
    __shared__ float4 sWt4[2][256];

    float* sF  = (float*)sF4;   float* sP  = (float*)sP4;
    float* sA  = (float*)sA4;   float* sAP = (float*)sAP4;
    float* sHP = (float*)sHP4;  float* sV  = (float*)sV4;
    float* sB  = (float*)sB4;   float* sS  = (float*)sS4;
    float* T1  = (float*)btf;   float* T2 = T1 + 256;  float* T3 = T1 + 512;
    float* eA  = (float*)eEf;   float* eC = eA + 256;  float* eJ = eA + 512;
    float* e2A = (float*)e2f;   float* e2C = e2A + 256; float* e2J = e2A + 512;
    float* oA  = (float*)eof;   float* oC = oA + 256;  float* oJ = oA + 512;
    float* sGt0 = (float*)sGt4[0]; float* sGt1 = (float*)sGt4[1];
    float* sWt0 = (float*)sWt4[0]; float* sWt1 = (float*)sWt4[1];

    const int tid = threadIdx.x;
    const int q  = tid >> 4, j = tid & 15;
    const int bi = tid >> 2, bm = tid & 3;
    const int c  = blockIdx.x;               // chunk 0..15
    const int L  = (c == 15) ? 15 : 16;
    const int base = OPOFF + c*OPSZ;

    const float4* Fg4 = (const float4*)Fg;
    const float4* Hg4 = (const float4*)Hg;
    const float4* Rg4 = (const float4*)Rg;

    for (int u = tid; u < 256; u += 64) {
        sF[(u >> 4)*20 + (u & 15)] = Fg[u];
        sFd[u] = Fg[u];
    }
    for (int u = tid; u < 1024; u += 64) { sWt0[u] = 0.f; sWt1[u] = 0.f; }
    for (int u = tid; u < 256; u += 64) ws[base + HW_O + u] = 0.f;

    // ---- in-block chain: E^{16c} = prod over set bits of c of E^{16*2^bit} --
    if (c > 0) {
        bool have = false;
        for (int bit = 0; bit < 4; ++bit) {
            if (!((c >> bit) & 1)) continue;
            const float* src = ws + (4 + bit)*768;   // E^{16*2^bit}
            if (!have) {
                for (int u = tid; u < 768; u += 64) eA[u] = src[u];
                have = true;
                __syncthreads();
            } else {
                for (int u = tid; u < 768; u += 64) e2A[u] = src[u];
                __syncthreads();
                el_combine(eA, eC, eJ, e2A, e2C, e2J, oA, oC, oJ, bw, T1, T2, T3, tid);
                for (int u = tid; u < 768; u += 64) eA[u] = oA[u];
                __syncthreads();
            }
        }
    }

    // register preloads (R9-proven set)
    float4 zF[4][4], zFbi[4], zFj[4], zHq[4], zHn[4], zHm[4];
#pragma unroll
    for (int r = 0; r < 4; ++r)
#pragma unroll
        for (int f = 0; f < 4; ++f) zF[r][f] = Fg4[(q + 4*r)*4 + f];
#pragma unroll
    for (int f = 0; f < 4; ++f) {
        zFbi[f] = Fg4[bi*4 + f];
        zFj[f]  = Fg4[j*4 + f];
        zHq[f]  = Hg4[q*4 + f];
        zHn[f]  = Hg4[bm*4 + f];
        zHm[f]  = Hg4[((tid >> 2) & 3)*4 + f];
    }
    float zQ[4];
#pragma unroll
    for (int r = 0; r < 4; ++r) zQ[r] = Qg[(q + 4*r)*16 + j];
    float  zRs = Rg[tid & 15];
    float4 zR4[4];
#pragma unroll
    for (int m = 0; m < 4; ++m) zR4[m] = Rg4[m];
    float4 zHcjv = make_float4(Hg[j], Hg[16 + j], Hg[32 + j], Hg[48 + j]);
    float4 zFijv = make_float4(Fg[q*16 + j],     Fg[(q+4)*16 + j],
                               Fg[(q+8)*16 + j], Fg[(q+12)*16 + j]);
    float4 zSd2[4];
    float  sd2[16];
#pragma unroll
    for (int f = 0; f < 4; ++f) {
        float4 s = ((const float4*)sdg)[f];
        zSd2[f] = make_float4(s.x*s.x, s.y*s.y, s.z*s.z, s.w*s.w);
        sd2[f*4+0] = s.x*s.x; sd2[f*4+1] = s.y*s.y;
        sd2[f*4+2] = s.z*s.z; sd2[f*4+3] = s.w*s.w;
    }
    __syncthreads();

    // ---- P_start -> sP (stride 20) ----
    if (c == 0) {
#pragma unroll
        for (int r = 0; r < 4; ++r) {
            float acc = zQ[r];
#pragma unroll
            for (int f = 0; f < 4; ++f) {
                float4 a = zF[r][f], b = zFj[f], s = zSd2[f];
                acc += a.x*s.x*b.x + a.y*s.y*b.y + a.z*s.z*b.z + a.w*s.w*b.w;
            }
            sP[(q + 4*r)*20 + j] = acc;
        }
        __syncthreads();
    } else {
        float* pg = T2;   // dense P0 scratch
#pragma unroll
        for (int r = 0; r < 4; ++r) {
            int i = q + 4*r;
            float acc = Qg[i*16 + j];
#pragma unroll
            for (int k = 0; k < 16; ++k) acc += sFd[i*16 + k]*sd2[k]*sFd[j*16 + k];
            pg[i*16 + j] = acc;
        }
        __syncthreads();
        {   // W = I + P0*J
            float bc[16];
#pragma unroll
            for (int k = 0; k < 16; ++k) bc[k] = eJ[k*16 + j];
            float4 b0 = make_float4(bc[0],bc[1],bc[2],bc[3]);
            float4 b1 = make_float4(bc[4],bc[5],bc[6],bc[7]);
            float4 b2 = make_float4(bc[8],bc[9],bc[10],bc[11]);
            float4 b3 = make_float4(bc[12],bc[13],bc[14],bc[15]);
#pragma unroll
            for (int r = 0; r < 4; ++r) {
                int i = q + 4*r;
                const float4* Pr = (const float4*)(pg + i*16);
                float acc = (i == j) ? 1.f : 0.f;
                acc += dot4(Pr[0],b0) + dot4(Pr[1],b1) + dot4(Pr[2],b2) + dot4(Pr[3],b3);
                bw[i*36 + j] = acc;
            }
        }
        __syncthreads();
        gj_invert16(bw, T1, tid);           // X
        __syncthreads();
        mm_nn(T1, pg, nullptr, T3, q, j);   // G = X*P0
        __syncthreads();
#pragma unroll
        for (int r = 0; r < 4; ++r) {       // symmetrize -> T1
            int i = q + 4*r;
            T1[i*16 + j] = 0.5f*(T3[i*16 + j] + T3[j*16 + i]);
        }
        __syncthreads();
        mm_nn(eA, T1, nullptr, T3, q, j);   // U = A*G
        __syncthreads();
        mm_nt(T3, eA, eC, T2, q, j);        // P = U*A^T + C
        __syncthreads();
#pragma unroll
        for (int r = 0; r < 4; ++r) {
            int i = q + 4*r;
            sP[i*20 + j] = T2[i*16 + j];
        }
        __syncthreads();
    }

    // ---- init operators: Gt[0] = I ; HG_0 = H ----
#pragma unroll
    for (int r = 0; r < 4; ++r) {
        int i = q + 4*r;
        sGt0[j*16 + i] = (i == j) ? 1.f : 0.f;
    }
    ws[base + 0*64 + q*16 + j] = Hg[q*16 + j];
    __syncthreads();

    int cur = 0;
    for (int k = 0; k < L; ++k) {
        float* Gn = cur ? sGt0 : sGt1;
        float* Wn = cur ? sWt0 : sWt1;
        float4* Gc4 = cur ? sGt4[1] : sGt4[0];
        float4* Gn4 = cur ? sGt4[0] : sGt4[1];
        float4* Wn4 = cur ? sWt4[0] : sWt4[1];
        float4* Wc4 = cur ? sWt4[1] : sWt4[0];

        // ===== Riccati step (R9-proven) =====
        float4 zP[4];
#pragma unroll
        for (int f = 0; f < 4; ++f) zP[f] = sP4[j*5 + f];
        float tf[4], hp = 0.f;
#pragma unroll
        for (int r = 0; r < 4; ++r) {
            float acc = 0.f;
#pragma unroll
            for (int f = 0; f < 4; ++f) acc += dot4(zF[r][f], zP[f]);
            tf[r] = acc;
        }
#pragma unroll
        for (int f = 0; f < 4; ++f) hp += dot4(zHq[f], zP[f]);
        sHP[q*16 + j] = hp;
        __syncthreads();
        {
            float acc = 0.f;
#pragma unroll
            for (int f = 0; f < 4; ++f) acc += dot4(zFbi[f], sHP4[bm*4 + f]);
            sV[bi*4 + bm] = acc;
        }
        if (tid < 16) {
            float acc = zRs;
#pragma unroll
            for (int f = 0; f < 4; ++f) acc += dot4(sHP4[(tid >> 2)*4 + f], zHn[f]);
            sS[tid] = acc;
        }
        __syncthreads();
        {
            int ra = (bm == 0) ? 1 : 0;
            int rb = (bm <= 1) ? 2 : 1;
            int rc = (bm <= 2) ? 3 : 2;
            float4 a = sS4[ra], b = sS4[rb], cc = sS4[rc], sm = sS4[bm];
            float M0 = a.y*(b.z*cc.w - b.w*cc.z) - a.z*(b.y*cc.w - b.w*cc.y) + a.w*(b.y*cc.z - b.z*cc.y);
            float M1 = a.x*(b.z*cc.w - b.w*cc.z) - a.z*(b.x*cc.w - b.w*cc.x) + a.w*(b.x*cc.z - b.z*cc.x);
            float M2 = a.x*(b.y*cc.w - b.w*cc.y) - a.y*(b.x*cc.w - b.w*cc.x) + a.w*(b.x*cc.y - b.y*cc.x);
            float M3 = a.x*(b.y*cc.z - b.z*cc.y) - a.y*(b.x*cc.z - b.z*cc.x) + a.z*(b.x*cc.y - b.y*cc.x);
            float sg = (bm & 1) ? -1.f : 1.f;
            float c0 = sg*M0, c1 = -sg*M1, c2 = sg*M2, c3 = -sg*M3;
            float det = sm.x*c0 + sm.y*c1 + sm.z*c2 + sm.w*c3;
            float4 vv = sV4[bi];
            sB[tid] = (vv.x*c0 + vv.y*c1 + vv.z*c2 + vv.w*c3) / det;
        }
        __syncthreads();
        float4 bq[4], rbtv;
        {
            float4 hpcv = make_float4(sHP[j], sHP[16 + j], sHP[32 + j], sHP[48 + j]);
            float4 bj = sB4[j];
#pragma unroll
            for (int r = 0; r < 4; ++r) {
                int i = q + 4*r;
                bq[r] = sB4[i];
                sA[i*20 + j]  = ((const float*)&zFijv)[r] - dot4(bq[r], zHcjv);
                sAP[i*20 + j] = tf[r] - dot4(bq[r], hpcv);
            }
            rbtv = make_float4(dot4(zR4[0], bj), dot4(zR4[1], bj),
                               dot4(zR4[2], bj), dot4(zR4[3], bj));
        }
        __syncthreads();
        float4 zA[4];
#pragma unroll
        for (int f = 0; f < 4; ++f) zA[f] = sA4[j*5 + f];
#pragma unroll
        for (int r = 0; r < 4; ++r) {
            int i = q + 4*r;
            float acc = zQ[r] + dot4(bq[r], rbtv);
#pragma unroll
            for (int f = 0; f < 4; ++f) acc += dot4(sAP4[i*5 + f], zA[f]);
            sP[i*20 + j] = acc;
        }
        __syncthreads();   // sP done; sA/sB stable

        // ===== operator updates — STATIC loops (zeros propagate) =====
        {
            float4 gtj[4];
#pragma unroll
            for (int f = 0; f < 4; ++f) gtj[f] = Gc4[j*4 + f];
#pragma unroll
            for (int r = 0; r < 4; ++r) {
                int i = q + 4*r;
                const float4* Ar = (const float4*)(sA + i*20);
                Gn[j*16 + i] = dot4(Ar[0], gtj[0]) + dot4(Ar[1], gtj[1])
                             + dot4(Ar[2], gtj[2]) + dot4(Ar[3], gtj[3]);
            }
        }
        {
            int i2 = tid >> 2, n = tid & 3;
            const float4* Ai = (const float4*)(sA + i2*20);
            float4 a0 = Ai[0], a1 = Ai[1], a2 = Ai[2], a3 = Ai[3];
#pragma unroll
            for (int s = 0; s < 16; ++s) {
                float4 w0 = Wc4[s*16 + n*4 + 0], w1 = Wc4[s*16 + n*4 + 1],
                       w2 = Wc4[s*16 + n*4 + 2], w3 = Wc4[s*16 + n*4 + 3];
                Wn[s*64 + n*16 + i2] = dot4(a0,w0) + dot4(a1,w1) + dot4(a2,w2) + dot4(a3,w3);
            }
            Wn[k*64 + n*16 + i2] = sB[i2*4 + n];
        }
        __syncthreads();

        int k1 = k + 1;
        if (k1 <= 15) {
            {
                float4 g0 = Gn4[j*4 + 0], g1 = Gn4[j*4 + 1],
                       g2 = Gn4[j*4 + 2], g3 = Gn4[j*4 + 3];
                ws[base + k1*64 + q*16 + j] =
                    dot4(zHq[0],g0) + dot4(zHq[1],g1) + dot4(zHq[2],g2) + dot4(zHq[3],g3);
            }
            {
                int so = tid >> 4, m2 = (tid >> 2) & 3, n2 = tid & 3;
#pragma unroll
                for (int si = 0; si < 4; ++si) {
                    int s = so + 4*si;
                    float4 w0 = Wn4[s*16 + n2*4 + 0], w1 = Wn4[s*16 + n2*4 + 1],
                           w2 = Wn4[s*16 + n2*4 + 2], w3 = Wn4[s*16 + n2*4 + 3];
                    ws[base + HW_O + k1*256 + s*16 + m2*4 + n2] =
                        dot4(zHm[0],w0) + dot4(zHm[1],w1) + dot4(zHm[2],w2) + dot4(zHm[3],w3);
                }
            }
        }
        cur ^= 1;
        __syncthreads();
    }

    // ---- GL/WL for c<15 (final G = Gt[cur], W = Wt[cur]) ----
    if (c < 15) {
        float* Gc = cur ? sGt1 : sGt0;
        float* Wc = cur ? sWt1 : sWt0;
#pragma unroll
        for (int r = 0; r < 4; ++r) {
            int i = q + 4*r;
            ws[base + GL_O + i*16 + j] = Gc[j*16 + i];
        }
        int i2 = tid >> 2, n = tid & 3;
#pragma unroll
        for (int s = 0; s < 16; ++s)
            ws[base + WL_O + s*64 + i2*4 + n] = Wc[s*64 + n*16 + i2];
    }
}

// ---------------- K3: chunked affine filter, MULTI-WAVE ---------------------
// 64 blocks x 256 threads (4 waves), 16 batches/block. Pack staged ONCE per
// block and shared by 4 waves -> L2 broadcast traffic 105 MB -> 26 MB; 4
// waves/CU hide staging + LDS latency. LDS strides chosen for <=2-way banks
// (free): HG k-stride 18 f4, HW k-stride 66 f4 (264 floats ≡ 8 mod 32 ->
// 8*kb+4*m max 2-way), GL row-stride 5 f4, WL natural.
__global__ __launch_bounds__(256) void cfilter2_kernel(
    const float* __restrict__ obs, const float* __restrict__ Fg,
    const float* __restrict__ x0g, const float* __restrict__ ws,
    float* __restrict__ out)
{
    __shared__ float4 sPk4[1680];      // HG[0,288) HW[288,1344) GL[1344,1424) WL[1424,1680)
    __shared__ float4 sObs4v[16*17];   // [b][s] stride 17
    __shared__ float4 zLDS4[16*4];     // [b][f]
    __shared__ float4 sOutF4[16*17];   // [b][k] stride 17
    float* zLDS = (float*)zLDS4;
    float* sOut = (float*)sOutF4;

    const int tid = threadIdx.x;       // 0..255
    const int b = tid >> 4;            // local batch 0..15 (16 lanes each, wave-aligned)
    const int i = tid & 15;            // state / k-slot index
    const int m = i & 3, kb = i >> 2;

    // z0 = F x0
    {
        const float4* Fg4 = (const float4*)Fg;
        const float4* x04 = (const float4*)x0g;
        float acc = 0.f;
#pragma unroll
        for (int f = 0; f < 4; ++f) acc += dot4(Fg4[i*4 + f], x04[f]);
        zLDS[b*16 + i] = acc;
    }

    const float4* wsf4 = (const float4*)ws;
    const float4* obs4 = (const float4*)obs;
    float4* out4 = (float4*)out;

    for (int c = 0; c < 16; ++c) {
        const int t0 = 16*c;
        const int L = (c == 15) ? 15 : 16;
        // stage pack (1600 f4 over 256 threads = ~6 each) with restride
        {
            const float4* src = wsf4 + (OPOFF + c*OPSZ)/4;
            for (int u = tid; u < 1600; u += 256) {
                int dst;
                if (u < 256)       { dst = (u >> 4)*18 + (u & 15); }
                else if (u < 1280) { int v = u - 256;  dst = 288 + (v >> 6)*66 + (v & 63); }
                else if (u < 1344) { int v = u - 1280; dst = 1344 + (v >> 2)*5 + (v & 3); }
                else               { dst = 1424 + (u - 1344); }
                sPk4[dst] = src[u];
            }
        }
        {   // obs: one slot per thread, ss<L guard (R8 lesson)
            int ss = tid & 15, bb = tid >> 4;
            if (ss < L)
                sObs4v[bb*17 + ss] = obs4[(blockIdx.x*16 + bb) * NT + t0 + ss];
        }
        __syncthreads();   // staging done (also: all prev-chunk flush reads done)

        float4 zv[4];
#pragma unroll
        for (int f = 0; f < 4; ++f) zv[f] = zLDS4[b*4 + f];
        // 4 outputs per lane: k = kb + 4r, measurement col m
#pragma unroll
        for (int r = 0; r < 4; ++r) {
            int k = kb + 4*r;
            const float4* hg = &sPk4[k*18 + m*4];
            float v = dot4(hg[0],zv[0]) + dot4(hg[1],zv[1])
                    + dot4(hg[2],zv[2]) + dot4(hg[3],zv[3]);
#pragma unroll
            for (int s = 0; s < 15; ++s) {   // HW[k][s]=0 for s>=k (exact)
                float4 hw = sPk4[288 + k*66 + s*4 + m];
                v += dot4(hw, sObs4v[b*17 + s]);
            }
            sOut[b*68 + k*4 + m] = v;
        }
        // z advance (c<15); zLDS[b] is wave-local -> no barrier needed
        if (c < 15) {
            const float4* gl = &sPk4[1344 + i*5];
            float zn = dot4(gl[0],zv[0]) + dot4(gl[1],zv[1])
                     + dot4(gl[2],zv[2]) + dot4(gl[3],zv[3]);
#pragma unroll
            for (int s = 0; s < 16; ++s) {
                float4 wl = sPk4[1424 + s*16 + i];
                zn += dot4(wl, sObs4v[b*17 + s]);
            }
            zLDS[b*16 + i] = zn;
        }
        __syncthreads();   // sOut complete across all waves
        {   // flush: 256 f4, coalesced per batch
            int bb = tid >> 4, kk = tid & 15;
            out4[(blockIdx.x*16 + bb) * NT + t0 + kk] = sOutF4[bb*17 + kk];
        }
    }
}

// ================= FALLBACK: proven R9 fused kernel (242 us) =================
__global__ __launch_bounds__(64) void kf_block_kernel(
    const float* __restrict__ obs, const float* __restrict__ Fg,
    const float* __restrict__ Hg,  const float* __restrict__ Qg,
    const float* __restrict__ Rg,  const float* __restrict__ x0g,
    const float* __restrict__ sdg, float* __restrict__ out)
{
    __shared__ float4 sF4[80], sP4[80], sA4[80], sAP4[80];
    __shared__ float4 sHP4[16], sV4[16], sB4[16], sS4[4];
    __shared__ float  sH[64], sZ[16];
    __shared__ float4 sObs4[1024], sOut4v[1024];

    float* sF  = (float*)sF4;   float* sP  = (float*)sP4;
    float* sA  = (float*)sA4;   float* sAP = (float*)sAP4;
    float* sHP = (float*)sHP4;  float* sV  = (float*)sV4;
    float* sB  = (float*)sB4;   float* sS  = (float*)sS4;
    float* sOut = (float*)sOut4v;

    const int tid = threadIdx.x;
    const int q  = tid >> 4, j = tid & 15;
    const int bi = tid >> 2, bm = tid & 3;
    const int gbase = tid & 48;

    const float4* Fg4 = (const float4*)Fg;
    const float4* Hg4 = (const float4*)Hg;
    const float4* Rg4 = (const float4*)Rg;
    const float4* obs4g = (const float4*)obs;

    for (int u = tid; u < 256; u += 64) sF[(u >> 4) * 20 + (u & 15)] = Fg[u];
    sH[tid] = Hg[tid];
    for (int u = tid; u < 1024; u += 64)
        sObs4[u] = obs4g[(blockIdx.x * 4 + (u >> 8)) * NT + (u & 255)];

    float4 zF[4][4], zFbi[4], zFj[4], zHq[4], zHn[4], zHrow4[4];
#pragma unroll
    for (int r = 0; r < 4; ++r)
#pragma unroll
        for (int f = 0; f < 4; ++f) zF[r][f] = Fg4[(q + 4*r)*4 + f];
#pragma unroll
    for (int f = 0; f < 4; ++f) {
        zFbi[f]   = Fg4[bi*4 + f];
        zFj[f]    = Fg4[j*4 + f];
        zHq[f]    = Hg4[q*4 + f];
        zHn[f]    = Hg4[bm*4 + f];
        zHrow4[f] = Hg4[(j & 3)*4 + f];
    }
    float hr[16] = {zHrow4[0].x,zHrow4[0].y,zHrow4[0].z,zHrow4[0].w,
                    zHrow4[1].x,zHrow4[1].y,zHrow4[1].z,zHrow4[1].w,
                    zHrow4[2].x,zHrow4[2].y,zHrow4[2].z,zHrow4[2].w,
                    zHrow4[3].x,zHrow4[3].y,zHrow4[3].z,zHrow4[3].w};
    float zQ[4];
#pragma unroll
    for (int r = 0; r < 4; ++r) zQ[r] = Qg[(q + 4*r)*16 + j];
    float  zRs = Rg[tid & 15];
    float4 zR4[4];
#pragma unroll
    for (int m = 0; m < 4; ++m) zR4[m] = Rg4[m];
    float4 zHcjv = make_float4(Hg[j], Hg[16 + j], Hg[32 + j], Hg[48 + j]);
    float4 zFijv = make_float4(Fg[q*16 + j],     Fg[(q+4)*16 + j],
                               Fg[(q+8)*16 + j], Fg[(q+12)*16 + j]);
    float4 zSd2[4];
#pragma unroll
    for (int f = 0; f < 4; ++f) {
        float4 s = ((const float4*)sdg)[f];
        zSd2[f] = make_float4(s.x*s.x, s.y*s.y, s.z*s.z, s.w*s.w);
    }
    __syncthreads();

#pragma unroll
    for (int r = 0; r < 4; ++r) {
        float acc = zQ[r];
#pragma unroll
        for (int f = 0; f < 4; ++f) {
            float4 a = zF[r][f], b = zFj[f], s = zSd2[f];
            acc += a.x*s.x*b.x + a.y*s.y*b.y + a.z*s.z*b.z + a.w*s.w*b.w;
        }
        sP[(q + 4*r)*20 + j] = acc;
    }
    if (tid < 16) {
        float acc = 0.f;
#pragma unroll
        for (int f = 0; f < 4; ++f) {
            float4 fr = ((float4*)(sF + tid*20))[f];
            float4 xv = ((const float4*)x0g)[f];
            acc += dot4(fr, xv);
        }
        sZ[tid] = acc;
    }
    __syncthreads();
    float zr = sZ[j];

    for (int t = 0; t < NSTEP; ++t) {
        float4 zP[4];
#pragma unroll
        for (int f = 0; f < 4; ++f) zP[f] = sP4[j*5 + f];
        float tf[4], hp = 0.f;
#pragma unroll
        for (int r = 0; r < 4; ++r) {
            float acc = 0.f;
#pragma unroll
            for (int f = 0; f < 4; ++f) acc += dot4(zF[r][f], zP[f]);
            tf[r] = acc;
        }
#pragma unroll
        for (int f = 0; f < 4; ++f) hp += dot4(zHq[f], zP[f]);
        sHP[q*16 + j] = hp;
        __syncthreads();
        {
            float acc = 0.f;
#pragma unroll
            for (int f = 0; f < 4; ++f) acc += dot4(zFbi[f], sHP4[bm*4 + f]);
            sV[bi*4 + bm] = acc;
        }
        if (tid < 16) {
            float acc = zRs;
#pragma unroll
            for (int f = 0; f < 4; ++f) acc += dot4(sHP4[(tid >> 2)*4 + f], zHn[f]);
            sS[tid] = acc;
        }
        __syncthreads();
        {
            int ra = (bm == 0) ? 1 : 0;
            int rb = (bm <= 1) ? 2 : 1;
            int rc = (bm <= 2) ? 3 : 2;
            float4 a = sS4[ra], b = sS4[rb], c = sS4[rc], sm = sS4[bm];
            float M0 = a.y*(b.z*c.w - b.w*c.z) - a.z*(b.y*c.w - b.w*c.y) + a.w*(b.y*c.z - b.z*c.y);
            float M1 = a.x*(b.z*c.w - b.w*c.z) - a.z*(b.x*c.w - b.w*c.x) + a.w*(b.x*c.z - b.z*c.x);
            float M2 = a.x*(b.y*c.w - b.w*c.y) - a.y*(b.x*c.w - b.w*c.x) + a.w*(b.x*c.y - b.y*c.x);
            float M3 = a.x*(b.y*c.z - b.z*c.y) - a.y*(b.x*c.z - b.z*c.x) + a.z*(b.x*c.y - b.y*c.x);
            float sg = (bm & 1) ? -1.f : 1.f;
            float c0 = sg*M0, c1 = -sg*M1, c2 = sg*M2, c3 = -sg*M3;
            float det = sm.x*c0 + sm.y*c1 + sm.z*c2 + sm.w*c3;
            float4 vv = sV4[bi];
            sB[tid] = (vv.x*c0 + vv.y*c1 + vv.z*c2 + vv.w*c3) / det;
        }
        __syncthreads();
        float4 bq[4], rbtv;
        {
            float4 hpcv = make_float4(sHP[j], sHP[16 + j], sHP[32 + j], sHP[48 + j]);
            float4 bj = sB4[j];
#pragma unroll
            for (int r = 0; r < 4; ++r) {
                int i = q + 4*r;
                bq[r] = sB4[i];
                sA[i*20 + j]  = ((const float*)&zFijv)[r] - dot4(bq[r], zHcjv);
                sAP[i*20 + j] = tf[r] - dot4(bq[r], hpcv);
            }
            rbtv = make_float4(dot4(zR4[0], bj), dot4(zR4[1], bj),
                               dot4(zR4[2], bj), dot4(zR4[3], bj));
        }
        __syncthreads();
        float4 zA[4];
#pragma unroll
        for (int f = 0; f < 4; ++f) zA[f] = sA4[j*5 + f];
#pragma unroll
        for (int r = 0; r < 4; ++r) {
            int i = q + 4*r;
            float acc = zQ[r] + dot4(bq[r], rbtv);
#pragma unroll
            for (int f = 0; f < 4; ++f) acc += dot4(sAP4[i*5 + f], zA[f]);
            sP[i*20 + j] = acc;
        }
        {
            float arr[16] = {zA[0].x,zA[0].y,zA[0].z,zA[0].w,
                             zA[1].x,zA[1].y,zA[1].z,zA[1].w,
                             zA[2].x,zA[2].y,zA[2].z,zA[2].w,
                             zA[3].x,zA[3].y,zA[3].z,zA[3].w};
            float4 bb = sB4[j];
            float4 oo = sObs4[q*256 + t];
            float o = 0.f, zn = dot4(bb, oo);
#pragma unroll
            for (int k = 0; k < 16; ++k) {
                float zk = __shfl(zr, gbase + k);
                o  = fmaf(hr[k],  zk, o);
                zn = fmaf(arr[k], zk, zn);
            }
            if (j < 4) sOut[(q*256 + t)*4 + j] = o;
            zr = zn;
        }
        __syncthreads();
    }
    {
        float o = 0.f;
#pragma unroll
        for (int k = 0; k < 16; ++k) {
            float zk = __shfl(zr, gbase + k);
            o = fmaf(hr[k], zk, o);
        }
        if (j < 4) sOut[(q*256 + 255)*4 + j] = o;
    }
    __syncthreads();
    float4* out4 = (float4*)out;
    for (int u = tid; u < 1024; u += 64)
        out4[(blockIdx.x * 4 + (u >> 8)) * NT + (u & 255)] = sOut4v[u];
}

extern "C" void kernel_launch(void* const* d_in, const int* in_sizes, int n_in,
                              void* d_out, int out_size, void* d_ws, size_t ws_size,
                              hipStream_t stream) {
    const float* obs = (const float*)d_in[0];   // [B,T,M]
    const float* F   = (const float*)d_in[1];   // [S,S]
    const float* H   = (const float*)d_in[2];   // [M,S]
    const float* Q   = (const float*)d_in[3];   // [S,S]
    const float* R   = (const float*)d_in[4];   // [M,M]
    const float* x0  = (const float*)d_in[5];   // [S]
    const float* sd  = (const float*)d_in[6];   // [S]
    float* ws  = (float*)d_ws;
    float* out = (float*)d_out;

    if (ws_size < NEED_WS_BYTES) {
        hipLaunchKernelGGL(kf_block_kernel, dim3(256), dim3(64), 0, stream,
                           obs, F, H, Q, R, x0, sd, out);
        return;
    }
    hipLaunchKernelGGL(scan_init_kernel, dim3(1),  dim3(64),  0, stream, F, H, Q, R, ws);
    hipLaunchKernelGGL(chunkop_kernel,   dim3(16), dim3(64),  0, stream, F, H, Q, R, sd, ws);
    hipLaunchKernelGGL(cfilter2_kernel,  dim3(64), dim3(256), 0, stream, obs, F, x0, ws, out);
}